// Round 12
// baseline (598.235 us; speedup 1.0000x reference)
//
#include <hip/hip_runtime.h>

// numpy never contracts mul+add: products are rounded then added. File-wide.
// The sgemm dot uses __builtin_fmaf explicitly (OpenBLAS vfmadd231ps).
#pragma clang fp contract(off)

#define NN 512
#define DD 256

typedef int   int4v   __attribute__((ext_vector_type(4)));

// ---------------------------------------------------------------------------
// Transpose emb [512][256] -> embT [256][512], classic 32x32 LDS tile.
// Coalesced on both sides; +1 pad kills bank conflicts.
// ---------------------------------------------------------------------------
__global__ __launch_bounds__(256)
void transpose_kernel(const float* __restrict__ in, float* __restrict__ outT)
{
    __shared__ float tile[32][33];
    const int tx = threadIdx.x;         // 0..31
    const int ty = threadIdx.y;         // 0..7
    const int bx = blockIdx.x;          // col tile 0..7  (DD/32)
    const int by = blockIdx.y;          // row tile 0..15 (NN/32)
    const int col = bx * 32 + tx;       // [0,256)
    #pragma unroll
    for (int i = 0; i < 32; i += 8)
        tile[ty + i][tx] = in[(size_t)(by * 32 + ty + i) * DD + col];
    __syncthreads();
    const int ocol = by * 32 + tx;      // [0,512)
    #pragma unroll
    for (int i = 0; i < 32; i += 8)
        outT[(size_t)(bx * 32 + ty + i) * NN + ocol] = tile[tx][ty + i];
}

// ---------------------------------------------------------------------------
// numpy f32 pairwise-sum leaf, n=128, AVX512 path — reading thread t's row
// from the TRANSPOSED matrix (embT[k*NN + t]), so wave lanes are coalesced.
// Identical values, identical op tree to the verified R11 version.
// ---------------------------------------------------------------------------
__device__ __forceinline__ float np_leaf128_T(const float* __restrict__ xT,
                                              const int t, const int base)
{
    float p[16];
    #pragma unroll
    for (int i = 0; i < 16; ++i) {
        const float x0 = xT[(size_t)(base + i      ) * NN + t];
        const float x1 = xT[(size_t)(base + i + 16 ) * NN + t];
        const float x2 = xT[(size_t)(base + i + 32 ) * NN + t];
        const float x3 = xT[(size_t)(base + i + 48 ) * NN + t];
        const float x4 = xT[(size_t)(base + i + 64 ) * NN + t];
        const float x5 = xT[(size_t)(base + i + 80 ) * NN + t];
        const float x6 = xT[(size_t)(base + i + 96 ) * NN + t];
        const float x7 = xT[(size_t)(base + i + 112) * NN + t];
        const float q0 = x0 * x0, q1 = x1 * x1, q2 = x2 * x2, q3 = x3 * x3;
        const float q4 = x4 * x4, q5 = x5 * x5, q6 = x6 * x6, q7 = x7 * x7;
        p[i] = ((q0 + q1) + (q2 + q3)) + ((q4 + q5) + (q6 + q7));
    }
    float q[8];
    #pragma unroll
    for (int i = 0; i < 8; ++i) q[i] = p[i] + p[i + 8];
    const float s0 = q[0] + q[4];
    const float s1 = q[1] + q[5];
    const float s2 = q[2] + q[6];
    const float s3 = q[3] + q[7];
    const float u0 = s0 + s2;
    const float u1 = s1 + s3;
    return u0 + u1;
}

// Original (uncoalesced) leaf — fallback path if ws is too small for embT.
__device__ __forceinline__ float np_leaf128(const float* __restrict__ x)
{
    float p[16];
    #pragma unroll
    for (int i = 0; i < 16; ++i) {
        const float q0 = x[i]       * x[i];
        const float q1 = x[i + 16]  * x[i + 16];
        const float q2 = x[i + 32]  * x[i + 32];
        const float q3 = x[i + 48]  * x[i + 48];
        const float q4 = x[i + 64]  * x[i + 64];
        const float q5 = x[i + 80]  * x[i + 80];
        const float q6 = x[i + 96]  * x[i + 96];
        const float q7 = x[i + 112] * x[i + 112];
        p[i] = ((q0 + q1) + (q2 + q3)) + ((q4 + q5) + (q6 + q7));
    }
    float q[8];
    #pragma unroll
    for (int i = 0; i < 8; ++i) q[i] = p[i] + p[i + 8];
    const float s0 = q[0] + q[4];
    const float s1 = q[1] + q[5];
    const float s2 = q[2] + q[6];
    const float s3 = q[3] + q[7];
    return (s0 + s2) + (s1 + s3);
}

// ---------------------------------------------------------------------------
// Fused TripletMarginMiner (verified bit-exact vs the numpy-f32 golden in
// R11). TRANSPOSED=1 reads thread-rows from embT for coalesced access.
//   sq   : np.sum(emb*emb,axis=1) — AVX512 pairwise leaves (above).
//   dot  : OpenBLAS sgemm — single f32 accumulator, sequential k, FMA.
//   mat  : fl32(fl32(sq_a+sq_j) - fl32(2*dot)), relu.
//   mask : sames(a,p)&(p!=a)&diffs(a,n)&(fl32(mat_an-mat_ap) <= 0.2f)
//          validity folded: dn=+inf (diff fails), mp=NaN (same fails).
// One block per anchor a; 512 threads; coalesced int4 stores, n fastest.
// ---------------------------------------------------------------------------
template <int TRANSPOSED>
__global__ __launch_bounds__(512)
void triplet_kernel(const float* __restrict__ emb,
                    const float* __restrict__ embT,
                    const int* __restrict__ lab,
                    int* __restrict__ out)
{
    __shared__ int   canon[NN];
    __shared__ float arow[DD];
    __shared__ float dn[NN];
    __shared__ float mp[NN];
    __shared__ float sq_a_sh;
    __shared__ int   det_lab64;

    const int a = blockIdx.x;
    const int t = threadIdx.x;   // 0..511

    // labels width canonicalization (values in [0,32): int64 staging has all
    // 256 odd int32 words zero; genuine int32 fails that w.p. 1-32^-256)
    if (t == 0) det_lab64 = 0;
    __syncthreads();
    if (t < 256 && lab[2 * t + 1] == 0) atomicAdd(&det_lab64, 1);
    __syncthreads();
    canon[t] = (det_lab64 == 256) ? lab[2 * t] : lab[t];

    if (t < DD) arow[t] = emb[(size_t)a * DD + t];
    __syncthreads();

    // ---- sq_j (numpy SIMD pairwise) and dot(a,j) (sgemm sequential FMA) ----
    float sqj, dot = 0.0f;
    if (TRANSPOSED) {
        sqj = np_leaf128_T(embT, t, 0) + np_leaf128_T(embT, t, 128);
        for (int k = 0; k < DD; ++k)
            dot = __builtin_fmaf(arow[k], embT[(size_t)k * NN + t], dot);
    } else {
        const float* __restrict__ xr = emb + (size_t)t * DD;
        sqj = np_leaf128(xr) + np_leaf128(xr + 128);
        for (int k = 0; k < DD; ++k)
            dot = __builtin_fmaf(arow[k], xr[k], dot);
    }
    if (t == a) sq_a_sh = sqj;
    __syncthreads();   // sq_a_sh visible

    // ---- mat[a][t], f32, numpy op tree ----
    const float t1 = sq_a_sh + sqj;
    const float t2 = 2.0f * dot;       // exact scale
    float m = t1 - t2;
    m = m > 0.0f ? m : 0.0f;

    const int la = canon[a];
    dn[t] = (canon[t] != la) ? m : __builtin_inff();
    mp[t] = (canon[t] == la && t != a) ? m : __builtin_nanf("");
    __syncthreads();

    // ---- write the 512x512 int32 slab, n fastest, coalesced int4 ----
    const int tx = t & 127;      // 4 consecutive n per thread
    const int ty = t >> 7;       // 0..3 strides p
    const float d0 = dn[4 * tx + 0];
    const float d1 = dn[4 * tx + 1];
    const float d2 = dn[4 * tx + 2];
    const float d3 = dn[4 * tx + 3];

    int4v* base = (int4v*)out + (size_t)a * NN * (NN / 4) + tx;
    for (int p = ty; p < NN; p += 4) {
        const float mpp = mp[p];             // LDS broadcast
        int4v r;
        r.x = ((d0 - mpp) <= 0.2f) ? 1 : 0;  // inf/NaN fold validity to 0
        r.y = ((d1 - mpp) <= 0.2f) ? 1 : 0;
        r.z = ((d2 - mpp) <= 0.2f) ? 1 : 0;
        r.w = ((d3 - mpp) <= 0.2f) ? 1 : 0;
        base[(size_t)p * (NN / 4)] = r;
    }
}

// ---------------------------------------------------------------------------
extern "C" void kernel_launch(void* const* d_in, const int* in_sizes, int n_in,
                              void* d_out, int out_size, void* d_ws, size_t ws_size,
                              hipStream_t stream)
{
    const float* emb    = (const float*)d_in[0];
    const int*   labels = (const int*)d_in[1];
    int*         out    = (int*)d_out;
    float*       embT   = (float*)d_ws;     // 512 KiB needed

    if (ws_size >= (size_t)NN * DD * sizeof(float)) {
        dim3 tb(32, 8);
        dim3 tg(DD / 32, NN / 32);          // (8, 16)
        transpose_kernel<<<tg, tb, 0, stream>>>(emb, embT);
        triplet_kernel<1><<<NN, 512, 0, stream>>>(emb, embT, labels, out);
    } else {
        triplet_kernel<0><<<NN, 512, 0, stream>>>(emb, nullptr, labels, out);
    }
}